// Round 16
// baseline (5214.122 us; speedup 1.0000x reference)
//
#include <hip/hip_runtime.h>
#include <math.h>
#include <limits.h>

#define BATCH 8
#define BEAM 4
#define VOCAB 32000
#define DMODEL 1024
#define MAXSEQ 32
#define PAD_ID 0
#define BOS_ID 1
#define EOS_ID 2
#define NROWS 32        // BATCH*BEAM
#define NBLK 500        // partial blocks (64 cols each)
#define NPART 512       // padded partial stride

// ---------------- workspace layout (bytes) ---------------- (r10 layout)
// hT  [DMODEL][NROWS]   f32    @ 0        (131072)
// PMS [NROWS][NPART][2] f32    @ 131072   (131072)
// PV  [NROWS][NPART][4] f32    @ 262144   (262144)
// PI  [NROWS][NPART][4] i32    @ 524288   (262144)
// state @ 786432 (seqs/scores/finished/lengths/last_tok)
#define HT_OFF     0
#define PMS_OFF    131072
#define PV_OFF     262144
#define PI_OFF     524288
#define STATE_OFF  786432

__device__ __forceinline__ bool better(float av, int ai, float bv, int bi) {
  return (av > bv) || ((av == bv) && (ai < bi));
}

// sorted-descending insert, compile-time N
template<int N>
__device__ __forceinline__ void insN(float v, int i, float tv[N], int ti[N]) {
  if (better(v, i, tv[N-1], ti[N-1])) {
    tv[N-1] = v; ti[N-1] = i;
    #pragma unroll
    for (int j = N-1; j > 0; j--) {
      if (better(tv[j], ti[j], tv[j-1], ti[j-1])) {
        float fv = tv[j]; tv[j] = tv[j-1]; tv[j-1] = fv;
        int ii = ti[j]; ti[j] = ti[j-1]; ti[j-1] = ii;
      }
    }
  }
}

// per-row epilogue: wave-wide {max, sumexp, top4} for value v at column c
__device__ __forceinline__ void row_partials(
    float v, int c, int row, int p, int lane,
    float2* __restrict__ PMS, float4* __restrict__ PV, int4* __restrict__ PI) {
  float m = v;
  #pragma unroll
  for (int off = 32; off >= 1; off >>= 1) m = fmaxf(m, __shfl_xor(m, off));
  float s = expf(v - m);
  #pragma unroll
  for (int off = 32; off >= 1; off >>= 1) s += __shfl_xor(s, off);
  float myv = v; int myc = c; bool alive = true;
  float t4v[4]; int t4i[4];
  #pragma unroll
  for (int q = 0; q < 4; ++q) {
    float cv = alive ? myv : -INFINITY;
    int   ci = alive ? myc : INT_MAX;
    #pragma unroll
    for (int off = 32; off >= 1; off >>= 1) {
      float ov = __shfl_xor(cv, off);
      int   oi = __shfl_xor(ci, off);
      if (better(ov, oi, cv, ci)) { cv = ov; ci = oi; }
    }
    t4v[q] = cv; t4i[q] = ci;
    alive = alive && (ci != myc);
  }
  if (lane == 0) {
    PMS[row * NPART + p] = make_float2(m, s);
    PV[row * NPART + p]  = make_float4(t4v[0], t4v[1], t4v[2], t4v[3]);
    PI[row * NPART + p]  = make_int4(t4i[0], t4i[1], t4i[2], t4i[3]);
  }
}

// ---- kernel A: hT[c*32+r] = tanh(emb[tok_r] . Wdec[:,c] + b[c]) ----
template<bool INIT>
__global__ __launch_bounds__(256) void k_embdec(
    const float* __restrict__ emb, const float* __restrict__ Wdec,
    const float* __restrict__ bdec, const int* __restrict__ last_tok,
    float* __restrict__ hT) {
  __shared__ float red[4][2][64];
  int tid = threadIdx.x;
  int lane = tid & 63, wv = tid >> 6;
  int c = blockIdx.x * 64 + lane;
  int r0 = blockIdx.y * 2;
  int t0 = INIT ? BOS_ID : last_tok[r0];
  int t1 = INIT ? BOS_ID : last_tok[r0 + 1];
  const float* x0 = emb + (size_t)t0 * DMODEL + wv * 256;
  const float* x1 = emb + (size_t)t1 * DMODEL + wv * 256;
  const float* W  = Wdec + (size_t)(wv * 256) * DMODEL + c;
  float a0 = 0.f, a1 = 0.f;
  #pragma unroll 16
  for (int j = 0; j < 256; ++j) {
    float w = W[(size_t)j * DMODEL];
    a0 = fmaf(x0[j], w, a0);
    a1 = fmaf(x1[j], w, a1);
  }
  red[wv][0][lane] = a0;
  red[wv][1][lane] = a1;
  __syncthreads();
  if (wv == 0) {
    a0 = (red[0][0][lane] + red[1][0][lane]) + (red[2][0][lane] + red[3][0][lane]);
    a1 = (red[0][1][lane] + red[1][1][lane]) + (red[2][1][lane] + red[3][1][lane]);
    float bb = bdec[c];
    hT[(size_t)c * NROWS + r0]     = tanhf(a0 + bb);
    hT[(size_t)c * NROWS + r0 + 1] = tanhf(a1 + bb);
  }
}

// ---- kernel B v3 (INIT, 8 rows): acc[8]-per-lane, LDS-staged h (r10) ----
template<int NR>
__global__ __launch_bounds__(512, 4) void k_logits_v3(
    const float* __restrict__ hT, const float* __restrict__ Wout,
    float2* __restrict__ PMS, float4* __restrict__ PV, int4* __restrict__ PI) {
  constexpr int NCH = NR / 8;
  constexpr int NG  = NR / 4;
  __shared__ __attribute__((aligned(16))) float sH[8192];
  __shared__ __attribute__((aligned(16))) float red[4096];

  int tid = threadIdx.x;
  int lane = tid & 63;
  int kw  = tid >> 6;
  int c = blockIdx.x * 64 + lane;
  int p = blockIdx.x;

  float acc[NR];
  #pragma unroll
  for (int r = 0; r < NR; ++r) acc[r] = 0.f;

  const float* wcol = Wout + c;

  #pragma unroll 1
  for (int pass = 0; pass < 4; ++pass) {
    const float4* src = (const float4*)(hT + pass * 8192) + (size_t)tid * 4;
    float4 v0 = src[0], v1 = src[1], v2 = src[2], v3 = src[3];
    __syncthreads();
    {
      float4* dst = (float4*)sH + (size_t)tid * 4;
      dst[0] = v0; dst[1] = v1; dst[2] = v2; dst[3] = v3;
    }
    __syncthreads();

    const float* wp = wcol + (size_t)(pass * 256 + kw * 32) * VOCAB;
    const float* hb0 = sH + (kw * 32) * 32;
    #pragma unroll
    for (int u = 0; u < 32; ++u) {
      float w = wp[(size_t)u * VOCAB];
      #pragma unroll
      for (int g = 0; g < NG; ++g) {
        float4 h4 = *(const float4*)(hb0 + u * 32 + g * 4);
        acc[g * 4 + 0] = fmaf(h4.x, w, acc[g * 4 + 0]);
        acc[g * 4 + 1] = fmaf(h4.y, w, acc[g * 4 + 1]);
        acc[g * 4 + 2] = fmaf(h4.z, w, acc[g * 4 + 2]);
        acc[g * 4 + 3] = fmaf(h4.w, w, acc[g * 4 + 3]);
      }
    }
  }

  __syncthreads();
  #pragma unroll
  for (int cc = 0; cc < NCH; ++cc) {     // fully unrolled: static acc indices
    #pragma unroll
    for (int r8 = 0; r8 < 8; ++r8)
      red[(kw * 8 + r8) * 64 + lane] = acc[cc * 8 + r8];
    __syncthreads();
    float v = ((((((red[(0 * 8 + kw) * 64 + lane]
                  + red[(1 * 8 + kw) * 64 + lane])
                  + red[(2 * 8 + kw) * 64 + lane])
                  + red[(3 * 8 + kw) * 64 + lane])
                  + red[(4 * 8 + kw) * 64 + lane])
                  + red[(5 * 8 + kw) * 64 + lane])
                  + red[(6 * 8 + kw) * 64 + lane])
                  + red[(7 * 8 + kw) * 64 + lane];
    row_partials(v, c, cc * 8 + kw, p, lane, PMS, PV, PI);
    __syncthreads();
  }
}

// ---- kernel B v7 (decode, 32 rows): SGPR-h, no LDS in main loop ----
// grid NBLK=500 x 1024 thr = 16 waves, wave kw owns k in [kw*64, kw*64+64).
// Per k: h[k][0..31] read via wave-UNIFORM loads (s_load, lgkm-only; hT is
// read-only __restrict__ -> scalarizes, r3-proven) feeding 32 v_fmac with
// SGPR operand; W per-lane global b32 (vmcnt). No LDS staging -> no DS-pipe
// traffic, no barriers in the main loop; 16 waves/block x ~2 blocks/CU =
// 8 waves/SIMD to hide s_load + W latency (r3 was the same dataflow at only
// 2 waves/SIMD). Epilogue: static 16-way k-reduce (v6-proven) + fused
// {max,sumexp,top4}.
__global__ __launch_bounds__(1024) void k_logits_v7(
    const float* __restrict__ hT, const float* __restrict__ Wout,
    float2* __restrict__ PMS, float4* __restrict__ PV, int4* __restrict__ PI) {
  __shared__ __attribute__((aligned(16))) float red[8192];  // 32 KB (epilogue)

  int tid = threadIdx.x;
  int lane = tid & 63;
  int kw  = tid >> 6;                             // wave id 0..15
  int c = blockIdx.x * 64 + lane;
  int p = blockIdx.x;

  float acc[NROWS];
  #pragma unroll
  for (int r = 0; r < NROWS; ++r) acc[r] = 0.f;

  const float* wp = Wout + (size_t)(kw * 64) * VOCAB + c;
  const float* hb = hT + (kw * 64) * NROWS;       // wave-uniform

  #pragma unroll 4
  for (int u = 0; u < 64; ++u) {
    float w = wp[(size_t)u * VOCAB];              // per-lane global (vmcnt)
    const float* h = hb + u * NROWS;              // uniform -> s_load (lgkm)
    #pragma unroll
    for (int g = 0; g < 8; ++g) {
      float4 h4 = *(const float4*)(h + g * 4);    // s_load_dwordx4
      acc[g * 4 + 0] = fmaf(h4.x, w, acc[g * 4 + 0]);
      acc[g * 4 + 1] = fmaf(h4.y, w, acc[g * 4 + 1]);
      acc[g * 4 + 2] = fmaf(h4.z, w, acc[g * 4 + 2]);
      acc[g * 4 + 3] = fmaf(h4.w, w, acc[g * 4 + 3]);
    }
  }

  // ---- deterministic 16-way k-reduce + fused epilogue (fully static) ----
  #pragma unroll
  for (int cc = 0; cc < 4; ++cc) {
    __syncthreads();                  // red free (prev chunk's reads done)
    #pragma unroll
    for (int r8 = 0; r8 < 8; ++r8)
      red[(kw * 8 + r8) * 64 + lane] = acc[cc * 8 + r8];
    __syncthreads();
    if (kw < 8) {
      float v = red[(0 * 8 + kw) * 64 + lane];
      #pragma unroll
      for (int s = 1; s < 16; ++s)
        v += red[(s * 8 + kw) * 64 + lane];
      row_partials(v, c, cc * 8 + kw, p, lane, PMS, PV, PI);
    }
  }
}

// ---- kernel C: per-batch merge + state update. grid BATCH x 256 thr.
template<bool INIT>
__global__ __launch_bounds__(256) void k_batch(
    const float2* __restrict__ PMS, const float4* __restrict__ PV,
    const int4* __restrict__ PI,
    int* __restrict__ seqs, float* __restrict__ scores,
    int* __restrict__ finished, float* __restrict__ lengths,
    int* __restrict__ last_tok, int t, int wout, float* __restrict__ out) {
  __shared__ float s_lse[BEAM], s_base[BEAM];
  __shared__ int   s_fin[BEAM];
  __shared__ float s_v4[BEAM][4];
  __shared__ int   s_i4[BEAM][4];
  __shared__ float s_score[4];
  __shared__ int   s_beam[4], s_tok[4];

  int b = blockIdx.x, tid = threadIdx.x;
  int lane = tid & 63, wv = tid >> 6;
  const int R = INIT ? 1 : BEAM;

  if (wv < R) {
    int row = INIT ? b : b * BEAM + wv;
    float M = -INFINITY, S = 0.f;
    float lv[4]; int li[4];
    #pragma unroll
    for (int j = 0; j < 4; ++j) { lv[j] = -INFINITY; li[j] = INT_MAX; }
    for (int p = lane; p < NBLK; p += 64) {
      float2 ms = PMS[row * NPART + p];
      float4 pv = PV[row * NPART + p];
      int4   pi = PI[row * NPART + p];
      if (ms.x > M) { S = S * expf(M - ms.x) + ms.y; M = ms.x; }
      else          { S += ms.y * expf(ms.x - M); }
      insN<4>(pv.x, pi.x, lv, li);
      insN<4>(pv.y, pi.y, lv, li);
      insN<4>(pv.z, pi.z, lv, li);
      insN<4>(pv.w, pi.w, lv, li);
    }
    #pragma unroll
    for (int off = 32; off >= 1; off >>= 1) {
      float oM = __shfl_xor(M, off);
      float oS = __shfl_xor(S, off);
      float nM = fmaxf(M, oM);
      S = S * expf(M - nM) + oS * expf(oM - nM);
      M = nM;
    }
    int ptr = 0;
    float o4v[4]; int o4i[4];
    #pragma unroll
    for (int q = 0; q < 4; ++q) {
      float hv = -INFINITY; int hi = INT_MAX;
      #pragma unroll
      for (int j = 0; j < 4; ++j) { if (ptr == j) { hv = lv[j]; hi = li[j]; } }
      float cv = hv; int ci = hi;
      #pragma unroll
      for (int off = 32; off >= 1; off >>= 1) {
        float ov = __shfl_xor(cv, off);
        int   oi = __shfl_xor(ci, off);
        if (better(ov, oi, cv, ci)) { cv = ov; ci = oi; }
      }
      o4v[q] = cv; o4i[q] = ci;
      if (ci == hi && ci != INT_MAX) ptr++;
    }
    if (lane == 0) {
      s_lse[wv] = M + logf(S);
      #pragma unroll
      for (int q = 0; q < 4; ++q) { s_v4[wv][q] = o4v[q]; s_i4[wv][q] = o4i[q]; }
      s_base[wv] = INIT ? 0.f : scores[row];
      s_fin[wv]  = INIT ? 0 : finished[row];
    }
  }
  __syncthreads();

  if (tid == 0) {
    float fv[4]; int fi[4];
    #pragma unroll
    for (int q = 0; q < 4; ++q) { fv[q] = -INFINITY; fi[q] = INT_MAX; }
    for (int kk = 0; kk < R; ++kk) {
      if (s_fin[kk]) {
        insN<4>(s_base[kk], kk * VOCAB + PAD_ID, fv, fi);
      } else {
        float base = s_base[kk], lse = s_lse[kk];
        #pragma unroll
        for (int j = 0; j < 4; ++j)
          insN<4>(base + (s_v4[kk][j] - lse), kk * VOCAB + s_i4[kk][j], fv, fi);
      }
    }
    #pragma unroll
    for (int q = 0; q < 4; ++q) {
      s_score[q] = fv[q];
      s_beam[q]  = fi[q] / VOCAB;
      s_tok[q]   = fi[q] % VOCAB;
    }
  }
  __syncthreads();

  int k5 = tid >> 5, p5 = tid & 31;
  if (INIT) {
    if (tid < 128) {
      int val = (p5 == 0) ? BOS_ID : ((p5 == 1) ? s_tok[k5] : PAD_ID);
      seqs[(b * BEAM + k5) * MAXSEQ + p5] = val;
    }
    if (tid < 4) {
      scores[b * BEAM + tid]   = s_score[tid];
      finished[b * BEAM + tid] = (s_tok[tid] == EOS_ID) ? 1 : 0;
      lengths[b * BEAM + tid]  = 1.f;
      last_tok[b * BEAM + tid] = s_tok[tid];
    }
  } else {
    int sv = 0, oldfin = 0; float oldlen = 0.f;
    if (tid < 128) {
      sv = seqs[(b * BEAM + s_beam[k5]) * MAXSEQ + p5];
      if (p5 == t) sv = s_tok[k5];
    }
    if (tid < 4) {
      oldfin = finished[b * BEAM + s_beam[tid]];
      oldlen = lengths[b * BEAM + s_beam[tid]];
    }
    __syncthreads();
    if (tid < 128) {
      seqs[(b * BEAM + k5) * MAXSEQ + p5] = sv;
      if (wout) out[(b * BEAM + k5) * MAXSEQ + p5] = (float)sv;
    }
    if (tid < 4) {
      float nl = oldlen + (oldfin ? 0.f : 1.f);
      int   nf = (oldfin || (s_tok[tid] == EOS_ID)) ? 1 : 0;
      scores[b * BEAM + tid]   = s_score[tid];
      finished[b * BEAM + tid] = nf;
      lengths[b * BEAM + tid]  = nl;
      last_tok[b * BEAM + tid] = s_tok[tid];
      if (wout)
        out[BATCH * BEAM * MAXSEQ + b * BEAM + tid] =
            s_score[tid] / powf((5.f + nl) / 6.f, 0.6f);
    }
  }
}

extern "C" void kernel_launch(void* const* d_in, const int* in_sizes, int n_in,
                              void* d_out, int out_size, void* d_ws, size_t ws_size,
                              hipStream_t stream) {
  const float* emb  = (const float*)d_in[0];
  const float* Wdec = (const float*)d_in[1];
  const float* bdec = (const float*)d_in[2];
  const float* Wout = (const float*)d_in[3];
  float* out = (float*)d_out;

  char* ws = (char*)d_ws;
  float*  hT  = (float*) (ws + HT_OFF);
  float2* PMS = (float2*)(ws + PMS_OFF);
  float4* PV  = (float4*)(ws + PV_OFF);
  int4*   PI  = (int4*)  (ws + PI_OFF);
  int*   seqs     = (int*)  (ws + STATE_OFF);
  float* scores   = (float*)(ws + STATE_OFF + 4096);
  int*   finished = (int*)  (ws + STATE_OFF + 4224);
  float* lengths  = (float*)(ws + STATE_OFF + 4352);
  int*   last_tok = (int*)  (ws + STATE_OFF + 4480);

  // ---- initial step from <bos> (8 rows) ----
  k_embdec<true><<<dim3(DMODEL / 64, BATCH / 2), 256, 0, stream>>>(
      emb, Wdec, bdec, last_tok, hT);
  k_logits_v3<8><<<NBLK, 512, 0, stream>>>(hT, Wout, PMS, PV, PI);
  k_batch<true><<<BATCH, 256, 0, stream>>>(PMS, PV, PI, seqs, scores, finished,
                                           lengths, last_tok, 0, 0, out);

  // ---- decode steps t = 2..31 (32 rows each) ----
  for (int t = 2; t < MAXSEQ; t++) {
    k_embdec<false><<<dim3(DMODEL / 64, NROWS / 2), 256, 0, stream>>>(
        emb, Wdec, bdec, last_tok, hT);
    k_logits_v7<<<NBLK, 1024, 0, stream>>>(hT, Wout, PMS, PV, PI);
    k_batch<false><<<BATCH, 256, 0, stream>>>(PMS, PV, PI, seqs, scores,
                                              finished, lengths, last_tok, t,
                                              (t == MAXSEQ - 1) ? 1 : 0, out);
  }
}

// Round 17
// 2615.475 us; speedup vs baseline: 1.9936x; 1.9936x over previous
//
#include <hip/hip_runtime.h>
#include <math.h>
#include <limits.h>

#define BATCH 8
#define BEAM 4
#define VOCAB 32000
#define DMODEL 1024
#define MAXSEQ 32
#define PAD_ID 0
#define BOS_ID 1
#define EOS_ID 2
#define NROWS 32        // BATCH*BEAM
#define NBLK 500        // 64-col blocks (INIT / fallback)
#define NBLK32 1000     // 32-col blocks (v8 decode)
#define HT_OFF 0        // hT [DMODEL][NROWS] f32 @0 (131072 B); rest runtime

__device__ __forceinline__ bool better(float av, int ai, float bv, int bi) {
  return (av > bv) || ((av == bv) && (ai < bi));
}

// sorted-descending insert, compile-time N
template<int N>
__device__ __forceinline__ void insN(float v, int i, float tv[N], int ti[N]) {
  if (better(v, i, tv[N-1], ti[N-1])) {
    tv[N-1] = v; ti[N-1] = i;
    #pragma unroll
    for (int j = N-1; j > 0; j--) {
      if (better(tv[j], ti[j], tv[j-1], ti[j-1])) {
        float fv = tv[j]; tv[j] = tv[j-1]; tv[j-1] = fv;
        int ii = ti[j]; ti[j] = ti[j-1]; ti[j-1] = ii;
      }
    }
  }
}

// 64-lane-wave epilogue: {max, sumexp, top4} over 64 cols
__device__ __forceinline__ void row_partials64(
    float v, int c, int row, int p, int lane, int npart,
    float2* __restrict__ PMS, float4* __restrict__ PV, int4* __restrict__ PI) {
  float m = v;
  #pragma unroll
  for (int off = 32; off >= 1; off >>= 1) m = fmaxf(m, __shfl_xor(m, off));
  float s = expf(v - m);
  #pragma unroll
  for (int off = 32; off >= 1; off >>= 1) s += __shfl_xor(s, off);
  float myv = v; int myc = c; bool alive = true;
  float t4v[4]; int t4i[4];
  #pragma unroll
  for (int q = 0; q < 4; ++q) {
    float cv = alive ? myv : -INFINITY;
    int   ci = alive ? myc : INT_MAX;
    #pragma unroll
    for (int off = 32; off >= 1; off >>= 1) {
      float ov = __shfl_xor(cv, off);
      int   oi = __shfl_xor(ci, off);
      if (better(ov, oi, cv, ci)) { cv = ov; ci = oi; }
    }
    t4v[q] = cv; t4i[q] = ci;
    alive = alive && (ci != myc);
  }
  if (lane == 0) {
    PMS[row * npart + p] = make_float2(m, s);
    PV[row * npart + p]  = make_float4(t4v[0], t4v[1], t4v[2], t4v[3]);
    PI[row * npart + p]  = make_int4(t4i[0], t4i[1], t4i[2], t4i[3]);
  }
}

// 32-lane-group epilogue: {max, sumexp, top4} over 32 cols (two rows/wave)
__device__ __forceinline__ void row_partials32(
    float v, int c, int row, int p, int c5, int npart,
    float2* __restrict__ PMS, float4* __restrict__ PV, int4* __restrict__ PI) {
  float m = v;
  #pragma unroll
  for (int off = 16; off >= 1; off >>= 1) m = fmaxf(m, __shfl_xor(m, off, 32));
  float s = expf(v - m);
  #pragma unroll
  for (int off = 16; off >= 1; off >>= 1) s += __shfl_xor(s, off, 32);
  float myv = v; int myc = c; bool alive = true;
  float t4v[4]; int t4i[4];
  #pragma unroll
  for (int q = 0; q < 4; ++q) {
    float cv = alive ? myv : -INFINITY;
    int   ci = alive ? myc : INT_MAX;
    #pragma unroll
    for (int off = 16; off >= 1; off >>= 1) {
      float ov = __shfl_xor(cv, off, 32);
      int   oi = __shfl_xor(ci, off, 32);
      if (better(ov, oi, cv, ci)) { cv = ov; ci = oi; }
    }
    t4v[q] = cv; t4i[q] = ci;
    alive = alive && (ci != myc);
  }
  if (c5 == 0) {
    PMS[row * npart + p] = make_float2(m, s);
    PV[row * npart + p]  = make_float4(t4v[0], t4v[1], t4v[2], t4v[3]);
    PI[row * npart + p]  = make_int4(t4i[0], t4i[1], t4i[2], t4i[3]);
  }
}

// ---- kernel A: hT[c*32+r] = tanh(emb[tok_r] . Wdec[:,c] + b[c]) ----
template<bool INIT>
__global__ __launch_bounds__(256) void k_embdec(
    const float* __restrict__ emb, const float* __restrict__ Wdec,
    const float* __restrict__ bdec, const int* __restrict__ last_tok,
    float* __restrict__ hT) {
  __shared__ float red[4][2][64];
  int tid = threadIdx.x;
  int lane = tid & 63, wv = tid >> 6;
  int c = blockIdx.x * 64 + lane;
  int r0 = blockIdx.y * 2;
  int t0 = INIT ? BOS_ID : last_tok[r0];
  int t1 = INIT ? BOS_ID : last_tok[r0 + 1];
  const float* x0 = emb + (size_t)t0 * DMODEL + wv * 256;
  const float* x1 = emb + (size_t)t1 * DMODEL + wv * 256;
  const float* W  = Wdec + (size_t)(wv * 256) * DMODEL + c;
  float a0 = 0.f, a1 = 0.f;
  #pragma unroll 16
  for (int j = 0; j < 256; ++j) {
    float w = W[(size_t)j * DMODEL];
    a0 = fmaf(x0[j], w, a0);
    a1 = fmaf(x1[j], w, a1);
  }
  red[wv][0][lane] = a0;
  red[wv][1][lane] = a1;
  __syncthreads();
  if (wv == 0) {
    a0 = (red[0][0][lane] + red[1][0][lane]) + (red[2][0][lane] + red[3][0][lane]);
    a1 = (red[0][1][lane] + red[1][1][lane]) + (red[2][1][lane] + red[3][1][lane]);
    float bb = bdec[c];
    hT[(size_t)c * NROWS + r0]     = tanhf(a0 + bb);
    hT[(size_t)c * NROWS + r0 + 1] = tanhf(a1 + bb);
  }
}

// ---- kernel B v3 (INIT + fallback): acc[NR]-per-lane, 64-col blocks ----
template<int NR>
__global__ __launch_bounds__(512, 4) void k_logits_v3(
    const float* __restrict__ hT, const float* __restrict__ Wout,
    float2* __restrict__ PMS, float4* __restrict__ PV, int4* __restrict__ PI,
    int npart) {
  constexpr int NCH = NR / 8;
  constexpr int NG  = NR / 4;
  __shared__ __attribute__((aligned(16))) float sH[8192];
  __shared__ __attribute__((aligned(16))) float red[4096];

  int tid = threadIdx.x;
  int lane = tid & 63;
  int kw  = tid >> 6;
  int c = blockIdx.x * 64 + lane;
  int p = blockIdx.x;

  float acc[NR];
  #pragma unroll
  for (int r = 0; r < NR; ++r) acc[r] = 0.f;

  const float* wcol = Wout + c;

  #pragma unroll 1
  for (int pass = 0; pass < 4; ++pass) {
    const float4* src = (const float4*)(hT + pass * 8192) + (size_t)tid * 4;
    float4 v0 = src[0], v1 = src[1], v2 = src[2], v3 = src[3];
    __syncthreads();
    {
      float4* dst = (float4*)sH + (size_t)tid * 4;
      dst[0] = v0; dst[1] = v1; dst[2] = v2; dst[3] = v3;
    }
    __syncthreads();

    const float* wp = wcol + (size_t)(pass * 256 + kw * 32) * VOCAB;
    const float* hb0 = sH + (kw * 32) * 32;
    #pragma unroll
    for (int u = 0; u < 32; ++u) {
      float w = wp[(size_t)u * VOCAB];
      #pragma unroll
      for (int g = 0; g < NG; ++g) {
        float4 h4 = *(const float4*)(hb0 + u * 32 + g * 4);
        acc[g * 4 + 0] = fmaf(h4.x, w, acc[g * 4 + 0]);
        acc[g * 4 + 1] = fmaf(h4.y, w, acc[g * 4 + 1]);
        acc[g * 4 + 2] = fmaf(h4.z, w, acc[g * 4 + 2]);
        acc[g * 4 + 3] = fmaf(h4.w, w, acc[g * 4 + 3]);
      }
    }
  }

  __syncthreads();
  #pragma unroll
  for (int cc = 0; cc < NCH; ++cc) {     // fully unrolled: static acc indices
    #pragma unroll
    for (int r8 = 0; r8 < 8; ++r8)
      red[(kw * 8 + r8) * 64 + lane] = acc[cc * 8 + r8];
    __syncthreads();
    float v = ((((((red[(0 * 8 + kw) * 64 + lane]
                  + red[(1 * 8 + kw) * 64 + lane])
                  + red[(2 * 8 + kw) * 64 + lane])
                  + red[(3 * 8 + kw) * 64 + lane])
                  + red[(4 * 8 + kw) * 64 + lane])
                  + red[(5 * 8 + kw) * 64 + lane])
                  + red[(6 * 8 + kw) * 64 + lane])
                  + red[(7 * 8 + kw) * 64 + lane];
    row_partials64(v, c, cc * 8 + kw, p, lane, npart, PMS, PV, PI);
    __syncthreads();
  }
}

// ---- kernel B v8 (decode): v3 dataflow, 32-col blocks -> grid 1000 ----
// 512 thr = 8 waves; lane = (h<<5)|c5: col c5, rows h*16..h*16+15 (acc[16]).
// Wave kw covers k in 8 chunks: pass*128 + kw*16 + u. Per k: 1 coalesced
// global W b32 + 4 ds_read_b128 of h (2 addr groups across halves = free
// 2-way) + 16 FMAs -- per-output identical to v3. LDS = 16KB sH + 32KB red
// = 48KB -> 3 blocks/CU; grid 1000 > 768 -> 6 waves/SIMD (v3 had 3.9).
// acc[16] + transients ~50 VGPR < the 64 budget that 48KB LDS implies
// (r11 spilled needing ~100; v8 fits). Fully static epilogue (r13 lesson).
__global__ __launch_bounds__(512) void k_logits_v8(
    const float* __restrict__ hT, const float* __restrict__ Wout,
    float2* __restrict__ PMS, float4* __restrict__ PV, int4* __restrict__ PI,
    int npart) {
  __shared__ __attribute__((aligned(16))) float sH[4096];   // 16KB: 128k x 32r
  __shared__ __attribute__((aligned(16))) float red[8192];  // 32KB: 8x32x32

  int tid = threadIdx.x;
  int lane = tid & 63;
  int kw  = tid >> 6;                   // wave 0..7
  int h   = lane >> 5;                  // row-half 0..1
  int c5  = lane & 31;                  // col within block
  int c = blockIdx.x * 32 + c5;
  int p = blockIdx.x;

  float acc[16];
  #pragma unroll
  for (int r = 0; r < 16; ++r) acc[r] = 0.f;

  const float* wcol = Wout + c;

  #pragma unroll 1
  for (int pass = 0; pass < 8; ++pass) {
    // stage 128k x 32r h tile: linear 16 KB copy (2 float4 / thread)
    const float4* src = (const float4*)(hT + pass * 4096) + (size_t)tid * 2;
    float4 v0 = src[0], v1 = src[1];
    __syncthreads();                    // previous pass's sH reads complete
    {
      float4* dst = (float4*)sH + (size_t)tid * 2;
      dst[0] = v0; dst[1] = v1;
    }
    __syncthreads();                    // tile visible

    const float* wp = wcol + (size_t)(pass * 128 + kw * 16) * VOCAB;
    const float* hb0 = sH + (kw * 16) * 32 + h * 16;  // 2 addr groups (free)
    #pragma unroll
    for (int u = 0; u < 16; ++u) {
      float w = wp[(size_t)u * VOCAB];            // coalesced global (vmcnt)
      #pragma unroll
      for (int q = 0; q < 4; ++q) {
        float4 h4 = *(const float4*)(hb0 + u * 32 + q * 4);  // ds b128 (lgkm)
        acc[q * 4 + 0] = fmaf(h4.x, w, acc[q * 4 + 0]);
        acc[q * 4 + 1] = fmaf(h4.y, w, acc[q * 4 + 1]);
        acc[q * 4 + 2] = fmaf(h4.z, w, acc[q * 4 + 2]);
        acc[q * 4 + 3] = fmaf(h4.w, w, acc[q * 4 + 3]);
      }
    }
  }

  // ---- deterministic 8-way k-reduce + fused epilogue (fully static) ----
  __syncthreads();                      // last pass's sH reads done
  #pragma unroll
  for (int j = 0; j < 16; ++j)          // static acc indices
    red[(kw * 32 + h * 16 + j) * 32 + c5] = acc[j];
  __syncthreads();

  #pragma unroll
  for (int it = 0; it < 2; ++it) {
    int row = kw + h * 8 + it * 16;     // (kw,h,it) -> rows 0..31 bijective
    float v = ((((((red[(0 * 32 + row) * 32 + c5]
                  + red[(1 * 32 + row) * 32 + c5])
                  + red[(2 * 32 + row) * 32 + c5])
                  + red[(3 * 32 + row) * 32 + c5])
                  + red[(4 * 32 + row) * 32 + c5])
                  + red[(5 * 32 + row) * 32 + c5])
                  + red[(6 * 32 + row) * 32 + c5])
                  + red[(7 * 32 + row) * 32 + c5];
    row_partials32(v, c, row, p, c5, npart, PMS, PV, PI);
  }
}

// ---- kernel C: per-batch merge + state update. grid BATCH x 256 thr. ----
template<bool INIT>
__global__ __launch_bounds__(256) void k_batch(
    const float2* __restrict__ PMS, const float4* __restrict__ PV,
    const int4* __restrict__ PI, int npart, int nslots,
    int* __restrict__ seqs, float* __restrict__ scores,
    int* __restrict__ finished, float* __restrict__ lengths,
    int* __restrict__ last_tok, int t, int wout, float* __restrict__ out) {
  __shared__ float s_lse[BEAM], s_base[BEAM];
  __shared__ int   s_fin[BEAM];
  __shared__ float s_v4[BEAM][4];
  __shared__ int   s_i4[BEAM][4];
  __shared__ float s_score[4];
  __shared__ int   s_beam[4], s_tok[4];

  int b = blockIdx.x, tid = threadIdx.x;
  int lane = tid & 63, wv = tid >> 6;
  const int R = INIT ? 1 : BEAM;

  if (wv < R) {
    int row = INIT ? b : b * BEAM + wv;
    float M = -INFINITY, S = 0.f;
    float lv[4]; int li[4];
    #pragma unroll
    for (int j = 0; j < 4; ++j) { lv[j] = -INFINITY; li[j] = INT_MAX; }
    for (int p = lane; p < nslots; p += 64) {
      float2 ms = PMS[row * npart + p];
      float4 pv = PV[row * npart + p];
      int4   pi = PI[row * npart + p];
      if (ms.x > M) { S = S * expf(M - ms.x) + ms.y; M = ms.x; }
      else          { S += ms.y * expf(ms.x - M); }
      insN<4>(pv.x, pi.x, lv, li);
      insN<4>(pv.y, pi.y, lv, li);
      insN<4>(pv.z, pi.z, lv, li);
      insN<4>(pv.w, pi.w, lv, li);
    }
    #pragma unroll
    for (int off = 32; off >= 1; off >>= 1) {
      float oM = __shfl_xor(M, off);
      float oS = __shfl_xor(S, off);
      float nM = fmaxf(M, oM);
      S = S * expf(M - nM) + oS * expf(oM - nM);
      M = nM;
    }
    int ptr = 0;
    float o4v[4]; int o4i[4];
    #pragma unroll
    for (int q = 0; q < 4; ++q) {
      float hv = -INFINITY; int hi = INT_MAX;
      #pragma unroll
      for (int j = 0; j < 4; ++j) { if (ptr == j) { hv = lv[j]; hi = li[j]; } }
      float cv = hv; int ci = hi;
      #pragma unroll
      for (int off = 32; off >= 1; off >>= 1) {
        float ov = __shfl_xor(cv, off);
        int   oi = __shfl_xor(ci, off);
        if (better(ov, oi, cv, ci)) { cv = ov; ci = oi; }
      }
      o4v[q] = cv; o4i[q] = ci;
      if (ci == hi && ci != INT_MAX) ptr++;
    }
    if (lane == 0) {
      s_lse[wv] = M + logf(S);
      #pragma unroll
      for (int q = 0; q < 4; ++q) { s_v4[wv][q] = o4v[q]; s_i4[wv][q] = o4i[q]; }
      s_base[wv] = INIT ? 0.f : scores[row];
      s_fin[wv]  = INIT ? 0 : finished[row];
    }
  }
  __syncthreads();

  if (tid == 0) {
    float fv[4]; int fi[4];
    #pragma unroll
    for (int q = 0; q < 4; ++q) { fv[q] = -INFINITY; fi[q] = INT_MAX; }
    for (int kk = 0; kk < R; ++kk) {
      if (s_fin[kk]) {
        insN<4>(s_base[kk], kk * VOCAB + PAD_ID, fv, fi);
      } else {
        float base = s_base[kk], lse = s_lse[kk];
        #pragma unroll
        for (int j = 0; j < 4; ++j)
          insN<4>(base + (s_v4[kk][j] - lse), kk * VOCAB + s_i4[kk][j], fv, fi);
      }
    }
    #pragma unroll
    for (int q = 0; q < 4; ++q) {
      s_score[q] = fv[q];
      s_beam[q]  = fi[q] / VOCAB;
      s_tok[q]   = fi[q] % VOCAB;
    }
  }
  __syncthreads();

  int k5 = tid >> 5, p5 = tid & 31;
  if (INIT) {
    if (tid < 128) {
      int val = (p5 == 0) ? BOS_ID : ((p5 == 1) ? s_tok[k5] : PAD_ID);
      seqs[(b * BEAM + k5) * MAXSEQ + p5] = val;
    }
    if (tid < 4) {
      scores[b * BEAM + tid]   = s_score[tid];
      finished[b * BEAM + tid] = (s_tok[tid] == EOS_ID) ? 1 : 0;
      lengths[b * BEAM + tid]  = 1.f;
      last_tok[b * BEAM + tid] = s_tok[tid];
    }
  } else {
    int sv = 0, oldfin = 0; float oldlen = 0.f;
    if (tid < 128) {
      sv = seqs[(b * BEAM + s_beam[k5]) * MAXSEQ + p5];
      if (p5 == t) sv = s_tok[k5];
    }
    if (tid < 4) {
      oldfin = finished[b * BEAM + s_beam[tid]];
      oldlen = lengths[b * BEAM + s_beam[tid]];
    }
    __syncthreads();
    if (tid < 128) {
      seqs[(b * BEAM + k5) * MAXSEQ + p5] = sv;
      if (wout) out[(b * BEAM + k5) * MAXSEQ + p5] = (float)sv;
    }
    if (tid < 4) {
      float nl = oldlen + (oldfin ? 0.f : 1.f);
      int   nf = (oldfin || (s_tok[tid] == EOS_ID)) ? 1 : 0;
      scores[b * BEAM + tid]   = s_score[tid];
      finished[b * BEAM + tid] = nf;
      lengths[b * BEAM + tid]  = nl;
      last_tok[b * BEAM + tid] = s_tok[tid];
      if (wout)
        out[BATCH * BEAM * MAXSEQ + b * BEAM + tid] =
            s_score[tid] / powf((5.f + nl) / 6.f, 0.6f);
    }
  }
}

extern "C" void kernel_launch(void* const* d_in, const int* in_sizes, int n_in,
                              void* d_out, int out_size, void* d_ws, size_t ws_size,
                              hipStream_t stream) {
  const float* emb  = (const float*)d_in[0];
  const float* Wdec = (const float*)d_in[1];
  const float* bdec = (const float*)d_in[2];
  const float* Wout = (const float*)d_in[3];
  float* out = (float*)d_out;

  // runtime layout: npart=1024 (v8 decode, 1000 slots) if ws fits, else the
  // exact r10 path (npart=512, v3 decode, 500 slots).
  char* ws = (char*)d_ws;
  const size_t base = 131072;                       // hT bytes
  size_t need1024 = base + (size_t)1024 * NROWS * (8 + 16 + 16) + 4608;
  int npart = (ws_size >= need1024) ? 1024 : 512;

  size_t pms_off = base;
  size_t pv_off  = pms_off + (size_t)npart * NROWS * 8;
  size_t pi_off  = pv_off  + (size_t)npart * NROWS * 16;
  size_t st_off  = pi_off  + (size_t)npart * NROWS * 16;

  float*  hT  = (float*) (ws + HT_OFF);
  float2* PMS = (float2*)(ws + pms_off);
  float4* PV  = (float4*)(ws + pv_off);
  int4*   PI  = (int4*)  (ws + pi_off);
  int*   seqs     = (int*)  (ws + st_off);
  float* scores   = (float*)(ws + st_off + 4096);
  int*   finished = (int*)  (ws + st_off + 4224);
  float* lengths  = (float*)(ws + st_off + 4352);
  int*   last_tok = (int*)  (ws + st_off + 4480);

  // ---- initial step from <bos> (8 rows) ----
  k_embdec<true><<<dim3(DMODEL / 64, BATCH / 2), 256, 0, stream>>>(
      emb, Wdec, bdec, last_tok, hT);
  k_logits_v3<8><<<NBLK, 512, 0, stream>>>(hT, Wout, PMS, PV, PI, npart);
  k_batch<true><<<BATCH, 256, 0, stream>>>(PMS, PV, PI, npart, NBLK, seqs,
                                           scores, finished, lengths, last_tok,
                                           0, 0, out);

  // ---- decode steps t = 2..31 (32 rows each) ----
  for (int t = 2; t < MAXSEQ; t++) {
    k_embdec<false><<<dim3(DMODEL / 64, NROWS / 2), 256, 0, stream>>>(
        emb, Wdec, bdec, last_tok, hT);
    if (npart == 1024) {
      k_logits_v8<<<NBLK32, 512, 0, stream>>>(hT, Wout, PMS, PV, PI, npart);
      k_batch<false><<<BATCH, 256, 0, stream>>>(
          PMS, PV, PI, npart, NBLK32, seqs, scores, finished, lengths,
          last_tok, t, (t == MAXSEQ - 1) ? 1 : 0, out);
    } else {
      k_logits_v3<32><<<NBLK, 512, 0, stream>>>(hT, Wout, PMS, PV, PI, npart);
      k_batch<false><<<BATCH, 256, 0, stream>>>(
          PMS, PV, PI, npart, NBLK, seqs, scores, finished, lengths,
          last_tok, t, (t == MAXSEQ - 1) ? 1 : 0, out);
    }
  }
}

// Round 18
// 2365.597 us; speedup vs baseline: 2.2041x; 1.1056x over previous
//
#include <hip/hip_runtime.h>
#include <math.h>
#include <limits.h>

#define BATCH 8
#define BEAM 4
#define VOCAB 32000
#define DMODEL 1024
#define MAXSEQ 32
#define PAD_ID 0
#define BOS_ID 1
#define EOS_ID 2
#define NROWS 32        // BATCH*BEAM
#define NBLK 500        // VOCAB/64 partial blocks
#define NPART 512       // padded partial stride

// ---------------- workspace layout (bytes) ----------------
// hT  [DMODEL][NROWS]   f32    @ 0        (131072)
// PMS [NROWS][NPART][2] f32    @ 131072   (131072)
// PV  [NROWS][NPART][4] f32    @ 262144   (262144)
// PI  [NROWS][NPART][4] i32    @ 524288   (262144)
// state @ 786432 (seqs/scores/finished/lengths/last_tok)
#define HT_OFF     0
#define PMS_OFF    131072
#define PV_OFF     262144
#define PI_OFF     524288
#define STATE_OFF  786432

__device__ __forceinline__ bool better(float av, int ai, float bv, int bi) {
  return (av > bv) || ((av == bv) && (ai < bi));
}

// sorted-descending insert, compile-time N
template<int N>
__device__ __forceinline__ void insN(float v, int i, float tv[N], int ti[N]) {
  if (better(v, i, tv[N-1], ti[N-1])) {
    tv[N-1] = v; ti[N-1] = i;
    #pragma unroll
    for (int j = N-1; j > 0; j--) {
      if (better(tv[j], ti[j], tv[j-1], ti[j-1])) {
        float fv = tv[j]; tv[j] = tv[j-1]; tv[j-1] = fv;
        int ii = ti[j]; ti[j] = ti[j-1]; ti[j-1] = ii;
      }
    }
  }
}

// per-row epilogue: wave-wide {max, sumexp, top4} for value v at column c
__device__ __forceinline__ void row_partials(
    float v, int c, int row, int p, int lane,
    float2* __restrict__ PMS, float4* __restrict__ PV, int4* __restrict__ PI) {
  float m = v;
  #pragma unroll
  for (int off = 32; off >= 1; off >>= 1) m = fmaxf(m, __shfl_xor(m, off));
  float s = expf(v - m);
  #pragma unroll
  for (int off = 32; off >= 1; off >>= 1) s += __shfl_xor(s, off);
  float myv = v; int myc = c; bool alive = true;
  float t4v[4]; int t4i[4];
  #pragma unroll
  for (int q = 0; q < 4; ++q) {
    float cv = alive ? myv : -INFINITY;
    int   ci = alive ? myc : INT_MAX;
    #pragma unroll
    for (int off = 32; off >= 1; off >>= 1) {
      float ov = __shfl_xor(cv, off);
      int   oi = __shfl_xor(ci, off);
      if (better(ov, oi, cv, ci)) { cv = ov; ci = oi; }
    }
    t4v[q] = cv; t4i[q] = ci;
    alive = alive && (ci != myc);
  }
  if (lane == 0) {
    PMS[row * NPART + p] = make_float2(m, s);
    PV[row * NPART + p]  = make_float4(t4v[0], t4v[1], t4v[2], t4v[3]);
    PI[row * NPART + p]  = make_int4(t4i[0], t4i[1], t4i[2], t4i[3]);
  }
}

// ---- kernel A: hT[c*32+r] = tanh(emb[tok_r] . Wdec[:,c] + b[c]) ----
template<bool INIT>
__global__ __launch_bounds__(256) void k_embdec(
    const float* __restrict__ emb, const float* __restrict__ Wdec,
    const float* __restrict__ bdec, const int* __restrict__ last_tok,
    float* __restrict__ hT) {
  __shared__ float red[4][2][64];
  int tid = threadIdx.x;
  int lane = tid & 63, wv = tid >> 6;
  int c = blockIdx.x * 64 + lane;
  int r0 = blockIdx.y * 2;
  int t0 = INIT ? BOS_ID : last_tok[r0];
  int t1 = INIT ? BOS_ID : last_tok[r0 + 1];
  const float* x0 = emb + (size_t)t0 * DMODEL + wv * 256;
  const float* x1 = emb + (size_t)t1 * DMODEL + wv * 256;
  const float* W  = Wdec + (size_t)(wv * 256) * DMODEL + c;
  float a0 = 0.f, a1 = 0.f;
  #pragma unroll 16
  for (int j = 0; j < 256; ++j) {
    float w = W[(size_t)j * DMODEL];
    a0 = fmaf(x0[j], w, a0);
    a1 = fmaf(x1[j], w, a1);
  }
  red[wv][0][lane] = a0;
  red[wv][1][lane] = a1;
  __syncthreads();
  if (wv == 0) {
    a0 = (red[0][0][lane] + red[1][0][lane]) + (red[2][0][lane] + red[3][0][lane]);
    a1 = (red[0][1][lane] + red[1][1][lane]) + (red[2][1][lane] + red[3][1][lane]);
    float bb = bdec[c];
    hT[(size_t)c * NROWS + r0]     = tanhf(a0 + bb);
    hT[(size_t)c * NROWS + r0 + 1] = tanhf(a1 + bb);
  }
}

// ---- kernel B v3: acc[NR]-per-lane GEMM + fused partials (r10-verified) ----
// grid NBLK=500 x 512 thr = 8 waves. Each LANE owns one column c and ALL NR
// rows (acc[NR]). k split 8-way across waves: per pass (256 k staged to LDS
// as a linear 32 KB copy), wave kw covers k in [pass*256 + kw*32, +32).
// Per k: 1 global b32 w-load (vmcnt, ~32 hoistable in the unrolled body)
// + NR/4 broadcast ds_read_b128 of h (lgkm, in-order, imm offsets, zero
// bank conflicts) + NR FMAs. No SMEM in the loop; no spill.
// Deterministic 8-way LDS reduce + fused epilogue.
template<int NR>
__global__ __launch_bounds__(512, 4) void k_logits_v3(
    const float* __restrict__ hT, const float* __restrict__ Wout,
    float2* __restrict__ PMS, float4* __restrict__ PV, int4* __restrict__ PI) {
  constexpr int NCH = NR / 8;                     // reduce chunks
  constexpr int NG  = NR / 4;                     // bcast groups per k
  __shared__ __attribute__((aligned(16))) float sH[8192];   // 32 KB h pass-tile
  __shared__ __attribute__((aligned(16))) float red[4096];  // 16 KB reduce

  int tid = threadIdx.x;
  int lane = tid & 63;
  int kw  = tid >> 6;                             // wave id 0..7
  int c = blockIdx.x * 64 + lane;
  int p = blockIdx.x;

  float acc[NR];
  #pragma unroll
  for (int r = 0; r < NR; ++r) acc[r] = 0.f;

  const float* wcol = Wout + c;

  #pragma unroll 1
  for (int pass = 0; pass < 4; ++pass) {
    // ---- stage pass-tile of h: linear 32 KB copy (hT is [k][32]) ----
    const float4* src = (const float4*)(hT + pass * 8192) + (size_t)tid * 4;
    float4 v0 = src[0], v1 = src[1], v2 = src[2], v3 = src[3];
    __syncthreads();                  // previous pass's reads complete
    {
      float4* dst = (float4*)sH + (size_t)tid * 4;
      dst[0] = v0; dst[1] = v1; dst[2] = v2; dst[3] = v3;
    }
    __syncthreads();                  // tile visible to all waves

    const float* wp = wcol + (size_t)(pass * 256 + kw * 32) * VOCAB;
    const float* hb0 = sH + (kw * 32) * 32;       // wave-uniform base
    #pragma unroll
    for (int u = 0; u < 32; ++u) {
      float w = wp[(size_t)u * VOCAB];            // global b32 (vmcnt)
      #pragma unroll
      for (int g = 0; g < NG; ++g) {
        float4 h4 = *(const float4*)(hb0 + u * 32 + g * 4);  // bcast (lgkm)
        acc[g * 4 + 0] = fmaf(h4.x, w, acc[g * 4 + 0]);
        acc[g * 4 + 1] = fmaf(h4.y, w, acc[g * 4 + 1]);
        acc[g * 4 + 2] = fmaf(h4.z, w, acc[g * 4 + 2]);
        acc[g * 4 + 3] = fmaf(h4.w, w, acc[g * 4 + 3]);
      }
    }
  }

  // ---- deterministic 8-way k-reduce + fused epilogue ----
  __syncthreads();                    // last pass's sH reads done (red separate)
  #pragma unroll 1
  for (int cc = 0; cc < NCH; ++cc) {
    #pragma unroll
    for (int r8 = 0; r8 < 8; ++r8)
      red[(kw * 8 + r8) * 64 + lane] = acc[cc * 8 + r8];
    __syncthreads();
    float v = ((((((red[(0 * 8 + kw) * 64 + lane]
                  + red[(1 * 8 + kw) * 64 + lane])
                  + red[(2 * 8 + kw) * 64 + lane])
                  + red[(3 * 8 + kw) * 64 + lane])
                  + red[(4 * 8 + kw) * 64 + lane])
                  + red[(5 * 8 + kw) * 64 + lane])
                  + red[(6 * 8 + kw) * 64 + lane])
                  + red[(7 * 8 + kw) * 64 + lane];
    row_partials(v, c, cc * 8 + kw, p, lane, PMS, PV, PI);
    __syncthreads();                  // before red is overwritten
  }
}

// ---- kernel C: per-batch merge + state update. grid BATCH x 256 thr.
template<bool INIT>
__global__ __launch_bounds__(256) void k_batch(
    const float2* __restrict__ PMS, const float4* __restrict__ PV,
    const int4* __restrict__ PI,
    int* __restrict__ seqs, float* __restrict__ scores,
    int* __restrict__ finished, float* __restrict__ lengths,
    int* __restrict__ last_tok, int t, int wout, float* __restrict__ out) {
  __shared__ float s_lse[BEAM], s_base[BEAM];
  __shared__ int   s_fin[BEAM];
  __shared__ float s_v4[BEAM][4];
  __shared__ int   s_i4[BEAM][4];
  __shared__ float s_score[4];
  __shared__ int   s_beam[4], s_tok[4];

  int b = blockIdx.x, tid = threadIdx.x;
  int lane = tid & 63, wv = tid >> 6;
  const int R = INIT ? 1 : BEAM;

  if (wv < R) {
    int row = INIT ? b : b * BEAM + wv;
    float M = -INFINITY, S = 0.f;
    float lv[4]; int li[4];
    #pragma unroll
    for (int j = 0; j < 4; ++j) { lv[j] = -INFINITY; li[j] = INT_MAX; }
    for (int p = lane; p < NBLK; p += 64) {
      float2 ms = PMS[row * NPART + p];
      float4 pv = PV[row * NPART + p];
      int4   pi = PI[row * NPART + p];
      if (ms.x > M) { S = S * expf(M - ms.x) + ms.y; M = ms.x; }
      else          { S += ms.y * expf(ms.x - M); }
      insN<4>(pv.x, pi.x, lv, li);
      insN<4>(pv.y, pi.y, lv, li);
      insN<4>(pv.z, pi.z, lv, li);
      insN<4>(pv.w, pi.w, lv, li);
    }
    #pragma unroll
    for (int off = 32; off >= 1; off >>= 1) {
      float oM = __shfl_xor(M, off);
      float oS = __shfl_xor(S, off);
      float nM = fmaxf(M, oM);
      S = S * expf(M - nM) + oS * expf(oM - nM);
      M = nM;
    }
    int ptr = 0;
    float o4v[4]; int o4i[4];
    #pragma unroll
    for (int q = 0; q < 4; ++q) {
      float hv = -INFINITY; int hi = INT_MAX;
      #pragma unroll
      for (int j = 0; j < 4; ++j) { if (ptr == j) { hv = lv[j]; hi = li[j]; } }
      float cv = hv; int ci = hi;
      #pragma unroll
      for (int off = 32; off >= 1; off >>= 1) {
        float ov = __shfl_xor(cv, off);
        int   oi = __shfl_xor(ci, off);
        if (better(ov, oi, cv, ci)) { cv = ov; ci = oi; }
      }
      o4v[q] = cv; o4i[q] = ci;
      if (ci == hi && ci != INT_MAX) ptr++;
    }
    if (lane == 0) {
      s_lse[wv] = M + logf(S);
      #pragma unroll
      for (int q = 0; q < 4; ++q) { s_v4[wv][q] = o4v[q]; s_i4[wv][q] = o4i[q]; }
      s_base[wv] = INIT ? 0.f : scores[row];
      s_fin[wv]  = INIT ? 0 : finished[row];
    }
  }
  __syncthreads();

  if (tid == 0) {
    float fv[4]; int fi[4];
    #pragma unroll
    for (int q = 0; q < 4; ++q) { fv[q] = -INFINITY; fi[q] = INT_MAX; }
    for (int kk = 0; kk < R; ++kk) {
      if (s_fin[kk]) {
        insN<4>(s_base[kk], kk * VOCAB + PAD_ID, fv, fi);
      } else {
        float base = s_base[kk], lse = s_lse[kk];
        #pragma unroll
        for (int j = 0; j < 4; ++j)
          insN<4>(base + (s_v4[kk][j] - lse), kk * VOCAB + s_i4[kk][j], fv, fi);
      }
    }
    #pragma unroll
    for (int q = 0; q < 4; ++q) {
      s_score[q] = fv[q];
      s_beam[q]  = fi[q] / VOCAB;
      s_tok[q]   = fi[q] % VOCAB;
    }
  }
  __syncthreads();

  int k5 = tid >> 5, p5 = tid & 31;
  if (INIT) {
    if (tid < 128) {
      int val = (p5 == 0) ? BOS_ID : ((p5 == 1) ? s_tok[k5] : PAD_ID);
      seqs[(b * BEAM + k5) * MAXSEQ + p5] = val;
    }
    if (tid < 4) {
      scores[b * BEAM + tid]   = s_score[tid];
      finished[b * BEAM + tid] = (s_tok[tid] == EOS_ID) ? 1 : 0;
      lengths[b * BEAM + tid]  = 1.f;
      last_tok[b * BEAM + tid] = s_tok[tid];
    }
  } else {
    int sv = 0, oldfin = 0; float oldlen = 0.f;
    if (tid < 128) {
      sv = seqs[(b * BEAM + s_beam[k5]) * MAXSEQ + p5];
      if (p5 == t) sv = s_tok[k5];
    }
    if (tid < 4) {
      oldfin = finished[b * BEAM + s_beam[tid]];
      oldlen = lengths[b * BEAM + s_beam[tid]];
    }
    __syncthreads();
    if (tid < 128) {
      seqs[(b * BEAM + k5) * MAXSEQ + p5] = sv;
      if (wout) out[(b * BEAM + k5) * MAXSEQ + p5] = (float)sv;
    }
    if (tid < 4) {
      float nl = oldlen + (oldfin ? 0.f : 1.f);
      int   nf = (oldfin || (s_tok[tid] == EOS_ID)) ? 1 : 0;
      scores[b * BEAM + tid]   = s_score[tid];
      finished[b * BEAM + tid] = nf;
      lengths[b * BEAM + tid]  = nl;
      last_tok[b * BEAM + tid] = s_tok[tid];
      if (wout)
        out[BATCH * BEAM * MAXSEQ + b * BEAM + tid] =
            s_score[tid] / powf((5.f + nl) / 6.f, 0.6f);
    }
  }
}

extern "C" void kernel_launch(void* const* d_in, const int* in_sizes, int n_in,
                              void* d_out, int out_size, void* d_ws, size_t ws_size,
                              hipStream_t stream) {
  const float* emb  = (const float*)d_in[0];
  const float* Wdec = (const float*)d_in[1];
  const float* bdec = (const float*)d_in[2];
  const float* Wout = (const float*)d_in[3];
  float* out = (float*)d_out;

  char* ws = (char*)d_ws;
  float*  hT  = (float*) (ws + HT_OFF);
  float2* PMS = (float2*)(ws + PMS_OFF);
  float4* PV  = (float4*)(ws + PV_OFF);
  int4*   PI  = (int4*)  (ws + PI_OFF);
  int*   seqs     = (int*)  (ws + STATE_OFF);
  float* scores   = (float*)(ws + STATE_OFF + 4096);
  int*   finished = (int*)  (ws + STATE_OFF + 4224);
  float* lengths  = (float*)(ws + STATE_OFF + 4352);
  int*   last_tok = (int*)  (ws + STATE_OFF + 4480);

  // ---- initial step from <bos> (8 rows) ----
  k_embdec<true><<<dim3(DMODEL / 64, BATCH / 2), 256, 0, stream>>>(
      emb, Wdec, bdec, last_tok, hT);
  k_logits_v3<8><<<NBLK, 512, 0, stream>>>(hT, Wout, PMS, PV, PI);
  k_batch<true><<<BATCH, 256, 0, stream>>>(PMS, PV, PI, seqs, scores, finished,
                                           lengths, last_tok, 0, 0, out);

  // ---- decode steps t = 2..31 (32 rows each) ----
  for (int t = 2; t < MAXSEQ; t++) {
    k_embdec<false><<<dim3(DMODEL / 64, NROWS / 2), 256, 0, stream>>>(
        emb, Wdec, bdec, last_tok, hT);
    k_logits_v3<32><<<NBLK, 512, 0, stream>>>(hT, Wout, PMS, PV, PI);
    k_batch<false><<<BATCH, 256, 0, stream>>>(PMS, PV, PI, seqs, scores,
                                              finished, lengths, last_tok, t,
                                              (t == MAXSEQ - 1) ? 1 : 0, out);
  }
}